// Round 19
// baseline (308.237 us; speedup 1.0000x reference)
//
#include <hip/hip_runtime.h>

// ---------------------------------------------------------------------------
// GIN 2-layer forward (bf16 features, MFMA GEMMs, CSR gather segment-sum):
//   CSR bucket edges by dst (hist -> single-kernel scan -> fill)
//   p1 = bf16( x @ w1a )                      [b1a cancels in BN]
//   s1 = bf16( p1[n] + gather-sum )           (fused column stats)
//   p2 = bf16( relu(BN(s1)) @ w1b + b1b, relu ) @ w2a   [FUSED mgemm23]
//   s2 = bf16( p2[n] + gather-sum )
//   out = log_softmax( relu(BN(s2)) @ w2b + b2b )  fp32, fused epilogue
// R18 = R15 structure + DETERMINISM FIX: fill_k's atomic bucket order varies
// per replay; fp32 segment sums were order-dependent and bf16 tie-flips
// produced 0.25 (= bf16 ulp at [32,64)) post-timing divergence in R17.
// Fix: segment sums accumulate in int64 fixed-point (scale 2^-24, exact per
// bf16 term, order-free); BN stats accumulate via u64 fixed-point atomics.
// Output is now bitwise identical across replays.
// segsum: R5 structure at the scattered-row-transaction wall (~96us each).
// ---------------------------------------------------------------------------

typedef unsigned short u16;
typedef unsigned int u32;
typedef unsigned long long u64;
typedef long long s64;
typedef __attribute__((ext_vector_type(8))) short short8;
typedef __attribute__((ext_vector_type(4))) short short4v;
typedef __attribute__((ext_vector_type(4))) float f32x4;

#define DEV_INLINE __device__ __forceinline__

#define FXS 16777216.0f            // 2^24 fixed-point scale
#define FXI 5.9604644775390625e-8f // 2^-24

DEV_INLINE u16 f2bf(float f) {
    unsigned u = __float_as_uint(f);
    u += 0x7fffu + ((u >> 16) & 1u);   // round-to-nearest-even
    return (u16)(u >> 16);
}
DEV_INLINE float bf2f(u16 h) { return __uint_as_float(((unsigned)h) << 16); }
DEV_INLINE s64 f2fx(float f) { return (s64)(f * FXS); }   // exact for bf16 in

// ---------------------------------------------------------------------------
// Weight prep (all 4 weights, one launch): W[K][NOUT] fp32 -> frag-ordered
// bf16. unit=(ct,kc,lane): 8 bf16 for col=ct*16+(lane&15), k=kc*32+(lane>>4)*8+j.
// ---------------------------------------------------------------------------
__global__ __launch_bounds__(256) void wprep4_k(
    const float* __restrict__ w1a, const float* __restrict__ w1b,
    const float* __restrict__ w2a, const float* __restrict__ w2b,
    short* __restrict__ o1a, short* __restrict__ o1b,
    short* __restrict__ o2a, short* __restrict__ o2b)
{
    int b = blockIdx.x;
    const float* W; short* wf; int K, NOUT;
    if (b < 8)       { W = w1a; wf = o1a; K = 128; NOUT = 128; }
    else if (b < 16) { W = w1b; wf = o1b; K = 128; NOUT = 128; b -= 8; }
    else if (b < 20) { W = w2a; wf = o2a; K = 128; NOUT = 64;  b -= 16; }
    else             { W = w2b; wf = o2b; K = 64;  NOUT = 64;  b -= 20; }
    const int u = b * 256 + threadIdx.x;
    const int units = (NOUT / 16) * (K / 32) * 64;
    if (u >= units) return;
    const int per_ct = (K / 32) * 64;
    const int ct = u / per_ct;
    const int rem = u % per_ct;
    const int kc = rem >> 6;
    const int l = rem & 63;
    const int col = ct * 16 + (l & 15);
    const int k0 = kc * 32 + (l >> 4) * 8;
    short8 pk;
#pragma unroll
    for (int j = 0; j < 8; j++)
        pk[j] = (short)f2bf(W[(size_t)(k0 + j) * NOUT + col]);
    *(short8*)&wf[(size_t)u * 8] = pk;
}

// ---------------------------------------------------------------------------
// mgemm1: p1 = bf16( x @ w1a ).  Reg-B: wave w holds col-tiles {2w,2w+1};
// LDS only for the A tile (16KB).
// ---------------------------------------------------------------------------
__global__ __launch_bounds__(256) void mgemm1_k(
    const float* __restrict__ x, const short* __restrict__ wf,
    u16* __restrict__ p1, int M)
{
    constexpr int KD = 128, NC = 128, KC = 4, KQ = 32;
    __shared__ short Asl[64 * KD];
    const int t = threadIdx.x;
    const int l = t & 63;
    const int w = t >> 6;

    short8 B[2][KC];
#pragma unroll
    for (int c = 0; c < 2; c++)
#pragma unroll
        for (int kc = 0; kc < KC; kc++)
            B[c][kc] = *(const short8*)&wf[(((w * 2 + c) * KC + kc) * 64 + l) * 8];

    {
        const int r = t >> 2;
        const int q = t & 3;
        const int grow = blockIdx.x * 64 + r;
        const int rt = r >> 4;
        u16 hv[KQ];
        if (grow < M) {
            const float* ap = x + (size_t)grow * KD + q * KQ;
#pragma unroll
            for (int i = 0; i < KQ / 4; i++) {
                const float4 v = ((const float4*)ap)[i];
                hv[i * 4 + 0] = f2bf(v.x); hv[i * 4 + 1] = f2bf(v.y);
                hv[i * 4 + 2] = f2bf(v.z); hv[i * 4 + 3] = f2bf(v.w);
            }
        } else {
#pragma unroll
            for (int i = 0; i < KQ; i++) hv[i] = 0;
        }
#pragma unroll
        for (int gg = 0; gg < KQ / 8; gg++) {
            const int k0 = q * KQ + gg * 8;
            const int kc = k0 >> 5;
            const int lane = (r & 15) + ((k0 >> 3) & 3) * 16;
            *(short8*)&Asl[((rt * KC + kc) * 64 + lane) * 8] = *(short8*)&hv[gg * 8];
        }
    }
    __syncthreads();

    f32x4 acc[4][2];
#pragma unroll
    for (int rt = 0; rt < 4; rt++)
#pragma unroll
        for (int c = 0; c < 2; c++) acc[rt][c] = (f32x4){0.f, 0.f, 0.f, 0.f};

#pragma unroll
    for (int kc = 0; kc < KC; kc++)
#pragma unroll
        for (int rt = 0; rt < 4; rt++) {
            const short8 x0 = *(const short8*)&Asl[((rt * KC + kc) * 64 + l) * 8];
            acc[rt][0] = __builtin_amdgcn_mfma_f32_16x16x32_bf16(B[0][kc], x0, acc[rt][0], 0, 0, 0);
            acc[rt][1] = __builtin_amdgcn_mfma_f32_16x16x32_bf16(B[1][kc], x0, acc[rt][1], 0, 0, 0);
        }

    const int cbase = (l >> 4) * 4;
#pragma unroll
    for (int rt = 0; rt < 4; rt++) {
        const int grow = blockIdx.x * 64 + rt * 16 + (l & 15);
        if (grow < M) {
#pragma unroll
            for (int c = 0; c < 2; c++) {
                short4v o16;
#pragma unroll
                for (int j = 0; j < 4; j++) o16[j] = (short)f2bf(acc[rt][c][j]);
                *(short4v*)&p1[(size_t)grow * NC + (w * 2 + c) * 16 + cbase] = o16;
            }
        }
    }
}

// ---------------------------------------------------------------------------
// FUSED mgemm23 (reg-B both stages): p2 = (relu(BN(s1))@w1b+b1b, relu) @ w2a
// BN stats arrive as fixed-point int64 (scale 2^24).
// ---------------------------------------------------------------------------
__global__ __launch_bounds__(256) void mgemm23_k(
    const u16* __restrict__ s1, const short* __restrict__ w1bf,
    const short* __restrict__ w2af,
    const u64* __restrict__ sum, const u64* __restrict__ sumsq,
    const float* __restrict__ g, const float* __restrict__ be, float invN,
    const float* __restrict__ b1b, u16* __restrict__ p2, int M)
{
    constexpr int KD = 128, NO = 64, KC = 4, KQ = 32;
    __shared__ short Asl[64 * KD];
    __shared__ float scb[KD];
    __shared__ float shb[KD];

    const int t = threadIdx.x;
    const int l = t & 63;
    const int w = t >> 6;

    short8 B1[2][KC];
    short8 B2[KC];
#pragma unroll
    for (int c = 0; c < 2; c++)
#pragma unroll
        for (int kc = 0; kc < KC; kc++)
            B1[c][kc] = *(const short8*)&w1bf[(((w * 2 + c) * KC + kc) * 64 + l) * 8];
#pragma unroll
    for (int kc = 0; kc < KC; kc++)
        B2[kc] = *(const short8*)&w2af[((w * KC + kc) * 64 + l) * 8];

    if (t < KD) {
        const float m = (float)((s64)sum[t]) * FXI * invN;
        const float v = (float)((s64)sumsq[t]) * FXI * invN - m * m;
        const float r = rsqrtf(v + 1e-5f);
        const float s = g[t] * r;
        scb[t] = s;
        shb[t] = be[t] - m * s;
    }
    __syncthreads();

    {
        const int r = t >> 2;
        const int q = t & 3;
        const int grow = blockIdx.x * 64 + r;
        const int rt = r >> 4;
        u16 hv[KQ];
        if (grow < M) {
            const u16* ap = s1 + (size_t)grow * KD + q * KQ;
#pragma unroll
            for (int i = 0; i < KQ / 8; i++)
                *(short8*)&hv[i * 8] = ((const short8*)ap)[i];
#pragma unroll
            for (int i = 0; i < KQ; i++) {
                const int k = q * KQ + i;
                hv[i] = f2bf(fmaxf(0.f, bf2f(hv[i]) * scb[k] + shb[k]));
            }
        } else {
#pragma unroll
            for (int i = 0; i < KQ; i++) hv[i] = 0;
        }
#pragma unroll
        for (int gg = 0; gg < KQ / 8; gg++) {
            const int k0 = q * KQ + gg * 8;
            const int kc = k0 >> 5;
            const int lane = (r & 15) + ((k0 >> 3) & 3) * 16;
            *(short8*)&Asl[((rt * KC + kc) * 64 + lane) * 8] = *(short8*)&hv[gg * 8];
        }
    }
    __syncthreads();

    f32x4 acc[4][2];
#pragma unroll
    for (int rt = 0; rt < 4; rt++)
#pragma unroll
        for (int c = 0; c < 2; c++) acc[rt][c] = (f32x4){0.f, 0.f, 0.f, 0.f};
#pragma unroll
    for (int kc = 0; kc < KC; kc++)
#pragma unroll
        for (int rt = 0; rt < 4; rt++) {
            const short8 x0 = *(const short8*)&Asl[((rt * KC + kc) * 64 + l) * 8];
            acc[rt][0] = __builtin_amdgcn_mfma_f32_16x16x32_bf16(B1[0][kc], x0, acc[rt][0], 0, 0, 0);
            acc[rt][1] = __builtin_amdgcn_mfma_f32_16x16x32_bf16(B1[1][kc], x0, acc[rt][1], 0, 0, 0);
        }
    __syncthreads();

    {
        const int cb4 = l >> 4;
#pragma unroll
        for (int rt = 0; rt < 4; rt++) {
            const int row = rt * 16 + (l & 15);
            const int sw = (row & 7) << 1;
#pragma unroll
            for (int c = 0; c < 2; c++) {
                const int ct = w * 2 + c;
                const float4 bv = *(const float4*)&b1b[ct * 16 + cb4 * 4];
                short4v o16;
                o16[0] = (short)f2bf(fmaxf(acc[rt][c][0] + bv.x, 0.f));
                o16[1] = (short)f2bf(fmaxf(acc[rt][c][1] + bv.y, 0.f));
                o16[2] = (short)f2bf(fmaxf(acc[rt][c][2] + bv.z, 0.f));
                o16[3] = (short)f2bf(fmaxf(acc[rt][c][3] + bv.w, 0.f));
                const int gsw = (ct * 4 + cb4) ^ sw;
                *(short4v*)&Asl[row * 128 + gsw * 4] = o16;
            }
        }
    }
    __syncthreads();

    f32x4 acc2[4];
#pragma unroll
    for (int rt = 0; rt < 4; rt++) acc2[rt] = (f32x4){0.f, 0.f, 0.f, 0.f};
#pragma unroll
    for (int kc = 0; kc < KC; kc++)
#pragma unroll
        for (int rt = 0; rt < 4; rt++) {
            const int row = rt * 16 + (l & 15);
            const int G = kc * 8 + (l >> 4) * 2;
            const int Gs = G ^ ((row & 7) << 1);
            const short8 x0 = *(const short8*)&Asl[row * 128 + Gs * 4];
            acc2[rt] = __builtin_amdgcn_mfma_f32_16x16x32_bf16(B2[kc], x0, acc2[rt], 0, 0, 0);
        }

    {
        const int cbase = (l >> 4) * 4;
#pragma unroll
        for (int rt = 0; rt < 4; rt++) {
            const int grow = blockIdx.x * 64 + rt * 16 + (l & 15);
            if (grow < M) {
                short4v o16;
#pragma unroll
                for (int j = 0; j < 4; j++) o16[j] = (short)f2bf(acc2[rt][j]);
                *(short4v*)&p2[(size_t)grow * NO + w * 16 + cbase] = o16;
            }
        }
    }
}

// ---------------------------------------------------------------------------
// mgemm4: out = log_softmax( relu(BN(s2)) @ w2b + b2b ).
// ---------------------------------------------------------------------------
__global__ __launch_bounds__(256) void mgemm4_k(
    const u16* __restrict__ s2, const short* __restrict__ Wf,
    const u64* __restrict__ sum, const u64* __restrict__ sumsq,
    const float* __restrict__ g, const float* __restrict__ be, float invN,
    const float* __restrict__ bias, float* __restrict__ outp, int M)
{
    constexpr int KD = 64, NC = 64, KC = 2, CT = 4, KQ = 16;
    __shared__ short Asl[64 * KD];
    __shared__ short Bsl[NC * KD];
    __shared__ float scb[KD];
    __shared__ float shb[KD];

    const int t = threadIdx.x;
    const int l = t & 63;
    const int w = t >> 6;

    if (t < KD) {
        const float m = (float)((s64)sum[t]) * FXI * invN;
        const float v = (float)((s64)sumsq[t]) * FXI * invN - m * m;
        const float r = rsqrtf(v + 1e-5f);
        const float s = g[t] * r;
        scb[t] = s;
        shb[t] = be[t] - m * s;
    }
    __syncthreads();

    {
        const float4* src = (const float4*)Wf;
        float4* dst = (float4*)Bsl;
#pragma unroll
        for (int u = t; u < NC * KD / 8; u += 256) dst[u] = src[u];
    }
    {
        const int r = t >> 2;
        const int q = t & 3;
        const int grow = blockIdx.x * 64 + r;
        const int rt = r >> 4;
        u16 hv[KQ];
        if (grow < M) {
            const u16* ap = s2 + (size_t)grow * KD + q * KQ;
#pragma unroll
            for (int i = 0; i < KQ / 8; i++)
                *(short8*)&hv[i * 8] = ((const short8*)ap)[i];
#pragma unroll
            for (int i = 0; i < KQ; i++) {
                const int k = q * KQ + i;
                hv[i] = f2bf(fmaxf(0.f, bf2f(hv[i]) * scb[k] + shb[k]));
            }
        } else {
#pragma unroll
            for (int i = 0; i < KQ; i++) hv[i] = 0;
        }
#pragma unroll
        for (int gg = 0; gg < KQ / 8; gg++) {
            const int k0 = q * KQ + gg * 8;
            const int kc = k0 >> 5;
            const int lane = (r & 15) + ((k0 >> 3) & 3) * 16;
            *(short8*)&Asl[((rt * KC + kc) * 64 + lane) * 8] = *(short8*)&hv[gg * 8];
        }
    }
    __syncthreads();

    f32x4 acc[CT];
#pragma unroll
    for (int c = 0; c < CT; c++) acc[c] = (f32x4){0.f, 0.f, 0.f, 0.f};
#pragma unroll
    for (int kc = 0; kc < KC; kc++) {
        const short8 x0 = *(const short8*)&Asl[((w * KC + kc) * 64 + l) * 8];
#pragma unroll
        for (int ct = 0; ct < CT; ct++) {
            const short8 wb = *(const short8*)&Bsl[((ct * KC + kc) * 64 + l) * 8];
            acc[ct] = __builtin_amdgcn_mfma_f32_16x16x32_bf16(wb, x0, acc[ct], 0, 0, 0);
        }
    }

    const int cbase = (l >> 4) * 4;
    const int grow = blockIdx.x * 64 + w * 16 + (l & 15);
    float v[CT * 4];
#pragma unroll
    for (int ct = 0; ct < CT; ct++) {
        const float4 bv = *(const float4*)&bias[ct * 16 + cbase];
        v[ct * 4 + 0] = acc[ct][0] + bv.x;
        v[ct * 4 + 1] = acc[ct][1] + bv.y;
        v[ct * 4 + 2] = acc[ct][2] + bv.z;
        v[ct * 4 + 3] = acc[ct][3] + bv.w;
    }
    float m = v[0];
#pragma unroll
    for (int j = 1; j < CT * 4; j++) m = fmaxf(m, v[j]);
    m = fmaxf(m, __shfl_xor(m, 16));
    m = fmaxf(m, __shfl_xor(m, 32));
    float s = 0.f;
#pragma unroll
    for (int j = 0; j < CT * 4; j++) s += __expf(v[j] - m);
    s += __shfl_xor(s, 16);
    s += __shfl_xor(s, 32);
    const float lg = m + __logf(s);
    if (grow < M) {
#pragma unroll
        for (int ct = 0; ct < CT; ct++) {
            f32x4 o;
#pragma unroll
            for (int j = 0; j < 4; j++) o[j] = v[ct * 4 + j] - lg;
            *(f32x4*)&outp[(size_t)grow * NC + ct * 16 + cbase] = o;
        }
    }
}

// ---------------------------------------------------------------------------
// CSR build: histogram (also zeroes agg), ONE-kernel scan, bucket fill.
// ---------------------------------------------------------------------------
__global__ __launch_bounds__(256) void hist_k(const int* __restrict__ ei,
                                              int* __restrict__ cnt,
                                              int* __restrict__ agg, int E)
{
    const int gid = blockIdx.x * blockDim.x + threadIdx.x;
    if (gid < 256) agg[gid] = 0;
    const int stride = gridDim.x * blockDim.x;
    for (int e = gid; e < E; e += stride) atomicAdd(&cnt[ei[E + e]], 1);
}

__global__ __launch_bounds__(256) void scan1_k(const int* __restrict__ cnt,
                                               int* __restrict__ agg,
                                               int* __restrict__ off,
                                               int* __restrict__ cursor,
                                               int N, int E)
{
    __shared__ int part[256];
    __shared__ int redu[256];
    const int t = threadIdx.x;
    const int b = blockIdx.x;
    const int i = b * 256 + t;
    const int v = (i < N) ? cnt[i] : 0;
    part[t] = v;
    __syncthreads();
    for (int d = 1; d < 256; d <<= 1) {
        const int u = (t >= d) ? part[t - d] : 0;
        __syncthreads();
        part[t] += u;
        __syncthreads();
    }
    if (t == 0)
        __hip_atomic_store(&agg[b], part[255] | (1 << 30), __ATOMIC_RELEASE,
                           __HIP_MEMORY_SCOPE_AGENT);
    int loc = 0;
    for (int pb = t; pb < b; pb += 256) {
        int a;
        do {
            a = __hip_atomic_load(&agg[pb], __ATOMIC_ACQUIRE,
                                  __HIP_MEMORY_SCOPE_AGENT);
        } while (!(a & (1 << 30)));
        loc += a & ((1 << 30) - 1);
    }
    redu[t] = loc;
    __syncthreads();
    for (int s = 128; s; s >>= 1) {
        if (t < s) redu[t] += redu[t + s];
        __syncthreads();
    }
    const int base = redu[0];
    if (i < N) {
        const int o = base + part[t] - v;
        off[i] = o;
        cursor[i] = o;
    }
    if (b == 0 && t == 0) off[N] = E;
}

__global__ __launch_bounds__(256) void fill_k(const int* __restrict__ ei,
                                              int* __restrict__ cursor,
                                              int* __restrict__ srcs, int E)
{
    const int gid = blockIdx.x * blockDim.x + threadIdx.x;
    const int stride = gridDim.x * blockDim.x;
    for (int e = gid; e < E; e += stride) {
        const int s = ei[e];
        const int d = ei[E + e];
        const int pos = atomicAdd(&cursor[d], 1);
        srcs[pos] = s;
    }
}

// ---------------------------------------------------------------------------
// Gather segment-sum (bf16 in/out) + fused column stats.
// [R5 structure, BLKN=8 occupancy sweet spot]
// DETERMINISM: node sums accumulate in int64 fixed-point (scale 2^24) --
// bf16->fixed conversion is exact, integer addition is order-free, so the
// result is invariant to fill_k's nondeterministic bucket order.
// Stats: per-block float partials (fixed order) -> u64 fixed-point atomics.
// ---------------------------------------------------------------------------
template <int C>
__global__ __launch_bounds__(256) void segsum_bf(
    const u16* __restrict__ p, const int* __restrict__ off,
    const int* __restrict__ srcs, u16* __restrict__ out,
    u64* __restrict__ sum, u64* __restrict__ sumsq, int N)
{
    constexpr int BLKN = 8;            // nodes per wave
    constexpr int VPL = C / 64;        // channels per lane (2 or 1)
    __shared__ float red[4][64][2 * VPL];

    const int wv = threadIdx.x >> 6;
    const int l  = threadIdx.x & 63;
    const int base = blockIdx.x * 4 * BLKN;

    float ss[VPL], qq[VPL];
#pragma unroll
    for (int v = 0; v < VPL; v++) { ss[v] = 0.f; qq[v] = 0.f; }

    for (int i = 0; i < BLKN; i++) {
        const int n = base + i * 4 + wv;
        if (n < N) {
            const int lo = __builtin_amdgcn_readfirstlane(off[n]);
            const int hi = __builtin_amdgcn_readfirstlane(off[n + 1]);
            s64 acc[VPL];
            if constexpr (VPL == 2) {
                const u32 u = *(const u32*)&p[(size_t)n * C + 2 * l];
                acc[0] = f2fx(bf2f((u16)u));
                acc[1] = f2fx(bf2f((u16)(u >> 16)));
            } else {
                acc[0] = f2fx(bf2f(p[(size_t)n * C + l]));
            }
            const int cnt = hi - lo;
            if (cnt > 0) {
                const int last = hi - 1;
                int idx[8];
#pragma unroll
                for (int j = 0; j < 8; j++) idx[j] = srcs[min(lo + j, last)];
                for (int e = lo; e < hi; e += 8) {
                    int nx[8];
#pragma unroll
                    for (int j = 0; j < 8; j++)
                        nx[j] = srcs[min(e + 8 + j, last)];   // prefetch next
#pragma unroll
                    for (int j = 0; j < 8; j++) {
                        const bool live = (e + j) < hi;
                        if constexpr (VPL == 2) {
                            const u32 u = *(const u32*)&p[(size_t)idx[j] * C + 2 * l];
                            const s64 t0 = f2fx(bf2f((u16)u));
                            const s64 t1 = f2fx(bf2f((u16)(u >> 16)));
                            acc[0] += live ? t0 : 0LL;
                            acc[1] += live ? t1 : 0LL;
                        } else {
                            const s64 t0 = f2fx(bf2f(p[(size_t)idx[j] * C + l]));
                            acc[0] += live ? t0 : 0LL;
                        }
                    }
#pragma unroll
                    for (int j = 0; j < 8; j++) idx[j] = nx[j];
                }
            }
            // fixed->float (one deterministic rounding), bf16 round, store
            if constexpr (VPL == 2) {
                const u16 r0 = f2bf((float)acc[0] * FXI);
                const u16 r1 = f2bf((float)acc[1] * FXI);
                *(u32*)&out[(size_t)n * C + 2 * l] = (u32)r0 | ((u32)r1 << 16);
                const float f0 = bf2f(r0), f1 = bf2f(r1);
                ss[0] += f0; qq[0] += f0 * f0;
                ss[1] += f1; qq[1] += f1 * f1;
            } else {
                const u16 r = f2bf((float)acc[0] * FXI);
                out[(size_t)n * C + l] = r;
                const float f = bf2f(r);
                ss[0] += f; qq[0] += f * f;
            }
        }
    }

    // block reduce (fixed order) -> u64 fixed-point atomics (order-free)
#pragma unroll
    for (int v = 0; v < VPL; v++) {
        red[wv][l][2 * v] = ss[v];
        red[wv][l][2 * v + 1] = qq[v];
    }
    __syncthreads();
    if (wv == 0) {
#pragma unroll
        for (int v = 0; v < VPL; v++) {
            float a = 0.f, b = 0.f;
#pragma unroll
            for (int w2 = 0; w2 < 4; w2++) {
                a += red[w2][l][2 * v];
                b += red[w2][l][2 * v + 1];
            }
            const int ch = (VPL == 2) ? (2 * l + v) : l;
            atomicAdd(&sum[ch], (u64)(s64)(a * FXS));
            atomicAdd(&sumsq[ch], (u64)(s64)(b * FXS));
        }
    }
}

extern "C" void kernel_launch(void* const* d_in, const int* in_sizes, int n_in,
                              void* d_out, int out_size, void* d_ws, size_t ws_size,
                              hipStream_t stream)
{
    const float* x   = (const float*)d_in[0];
    const int*   ei  = (const int*)d_in[1];
    const float* w1a = (const float*)d_in[2];
    // d_in[3] = b1a: cancelled by BN
    const float* g1  = (const float*)d_in[4];
    const float* be1 = (const float*)d_in[5];
    const float* w1b = (const float*)d_in[6];
    const float* b1b = (const float*)d_in[7];
    const float* w2a = (const float*)d_in[8];
    // d_in[9] = b2a: cancelled by BN
    const float* g2  = (const float*)d_in[10];
    const float* be2 = (const float*)d_in[11];
    const float* w2b = (const float*)d_in[12];
    const float* b2b = (const float*)d_in[13];
    float* out = (float*)d_out;

    const int N = in_sizes[0] / 128;   // 50000
    const int E = in_sizes[1] / 2;     // 800000

    // ---- workspace layout ----
    u16* buf1 = (u16*)d_ws;                      // N*128 bf16 : p1, then p2
    u16* buf2 = buf1 + (size_t)N * 128;          // N*128 bf16 : s1, then s2
    u64* statsll = (u64*)(buf2 + (size_t)N * 128);   // 384 u64 (fixed-point)
    u64* sum1 = statsll,       *sq1 = statsll + 128;
    u64* sum2 = statsll + 256, *sq2 = statsll + 320;
    int* cnt    = (int*)(statsll + 384);         // N
    int* off    = cnt + N;                       // N+1
    int* cursor = off + N + 1;                   // N
    int* srcs   = cursor + N;                    // E
    int* agg    = srcs + E;                      // 256 (scan aggregates)
    int* pad    = agg + 256;                     // 256 (alignment pad)
    short* w1af = (short*)(pad + 256);           // 128*128
    short* w1bf = w1af + 128 * 128;              // 128*128
    short* w2af = w1bf + 128 * 128;              // 128*64
    short* w2bf = w2af + 128 * 64;               // 64*64
    u16* p1 = buf1;
    u16* s1 = buf2;
    u16* p2 = buf1;                    // reuse: p1 dead after segsum1
    u16* s2 = buf2;                    // reuse: s1 dead after mgemm23

    hipMemsetAsync(statsll, 0, 384 * sizeof(u64) + (size_t)N * sizeof(int), stream);

    const int G1 = (N + 255) / 256;    // 196 blocks <= 256 CUs: co-resident
    const int gb = (N + 63) / 64;      // BM=64 -> 782 blocks
    const int gs = (N + 31) / 32;      // segsum: 4 waves x 8 nodes per block
    const float invN = 1.f / N;

    // ---- CSR build ----
    hist_k<<<1024, 256, 0, stream>>>(ei, cnt, agg, E);
    scan1_k<<<G1, 256, 0, stream>>>(cnt, agg, off, cursor, N, E);
    fill_k<<<1024, 256, 0, stream>>>(ei, cursor, srcs, E);

    // ---- weight prep (one launch for all four) ----
    wprep4_k<<<22, 256, 0, stream>>>(w1a, w1b, w2a, w2b, w1af, w1bf, w2af, w2bf);

    // ---- Layer 1 ----
    mgemm1_k<<<gb, 256, 0, stream>>>(x, w1af, p1, N);
    segsum_bf<128><<<gs, 256, 0, stream>>>(p1, off, srcs, s1, sum1, sq1, N);

    // ---- Fused: h1 = relu(BN(s1)@w1b+b1b); p2 = h1@w2a ----
    mgemm23_k<<<gb, 256, 0, stream>>>(s1, w1bf, w2af, sum1, sq1, g1, be1,
                                      invN, b1b, p2, N);

    // ---- Layer 2 aggregation + output ----
    segsum_bf<64><<<gs, 256, 0, stream>>>(p2, off, srcs, s2, sum2, sq2, N);
    mgemm4_k<<<gb, 256, 0, stream>>>(s2, w2bf, sum2, sq2, g2, be2, invN, b2b,
                                     out, N);
}

// Round 20
// 293.783 us; speedup vs baseline: 1.0492x; 1.0492x over previous
//
#include <hip/hip_runtime.h>

// ---------------------------------------------------------------------------
// GIN 2-layer forward (bf16 features, MFMA GEMMs, CSR gather segment-sum):
//   CSR bucket edges by dst (hist -> single-kernel scan -> fill)
//   p1 = bf16( x @ w1a )                      [b1a cancels in BN]
//   s1 = bf16( p1[n] + gather-sum )           (fused column stats)
//   p2 = bf16( relu(BN(s1)) @ w1b + b1b, relu ) @ w2a   [FUSED mgemm23]
//   s2 = bf16( p2[n] + gather-sum )
//   out = log_softmax( relu(BN(s2)) @ w2b + b2b )  fp32, fused epilogue
// R19 = R18 with a CHEAPER deterministic accumulator: segment sums use
// int32 fixed-point (scale 2^17) instead of int64 (scale 2^24). Any
// deterministic quantization + order-free integer sum is replay-invariant;
// int32 halves the VALU cost that R18 exposed (VALUBusy 54%).
// Range: |s|<=~64, deg<=~45 -> 3.8e8 << 2^31. Quantization <= 3.4e-4
// (negligible vs 0.031 error, 0.152 threshold).
// BN stats keep u64 fixed-point atomics (off critical path).
// segsum: R5 structure at the scattered-row-transaction wall.
// ---------------------------------------------------------------------------

typedef unsigned short u16;
typedef unsigned int u32;
typedef unsigned long long u64;
typedef long long s64;
typedef int s32;
typedef __attribute__((ext_vector_type(8))) short short8;
typedef __attribute__((ext_vector_type(4))) short short4v;
typedef __attribute__((ext_vector_type(4))) float f32x4;

#define DEV_INLINE __device__ __forceinline__

#define FXS 16777216.0f             // 2^24 (stats)
#define FXI 5.9604644775390625e-8f  // 2^-24
#define FXS2 131072.0f              // 2^17 (segment sums)
#define FXI2 7.62939453125e-6f      // 2^-17

DEV_INLINE u16 f2bf(float f) {
    unsigned u = __float_as_uint(f);
    u += 0x7fffu + ((u >> 16) & 1u);   // round-to-nearest-even
    return (u16)(u >> 16);
}
DEV_INLINE float bf2f(u16 h) { return __uint_as_float(((unsigned)h) << 16); }
DEV_INLINE s32 f2fx32(float f) { return (s32)(f * FXS2); }  // deterministic

// ---------------------------------------------------------------------------
// Weight prep (all 4 weights, one launch): W[K][NOUT] fp32 -> frag-ordered
// bf16. unit=(ct,kc,lane): 8 bf16 for col=ct*16+(lane&15), k=kc*32+(lane>>4)*8+j.
// ---------------------------------------------------------------------------
__global__ __launch_bounds__(256) void wprep4_k(
    const float* __restrict__ w1a, const float* __restrict__ w1b,
    const float* __restrict__ w2a, const float* __restrict__ w2b,
    short* __restrict__ o1a, short* __restrict__ o1b,
    short* __restrict__ o2a, short* __restrict__ o2b)
{
    int b = blockIdx.x;
    const float* W; short* wf; int K, NOUT;
    if (b < 8)       { W = w1a; wf = o1a; K = 128; NOUT = 128; }
    else if (b < 16) { W = w1b; wf = o1b; K = 128; NOUT = 128; b -= 8; }
    else if (b < 20) { W = w2a; wf = o2a; K = 128; NOUT = 64;  b -= 16; }
    else             { W = w2b; wf = o2b; K = 64;  NOUT = 64;  b -= 20; }
    const int u = b * 256 + threadIdx.x;
    const int units = (NOUT / 16) * (K / 32) * 64;
    if (u >= units) return;
    const int per_ct = (K / 32) * 64;
    const int ct = u / per_ct;
    const int rem = u % per_ct;
    const int kc = rem >> 6;
    const int l = rem & 63;
    const int col = ct * 16 + (l & 15);
    const int k0 = kc * 32 + (l >> 4) * 8;
    short8 pk;
#pragma unroll
    for (int j = 0; j < 8; j++)
        pk[j] = (short)f2bf(W[(size_t)(k0 + j) * NOUT + col]);
    *(short8*)&wf[(size_t)u * 8] = pk;
}

// ---------------------------------------------------------------------------
// mgemm1: p1 = bf16( x @ w1a ).  Reg-B: wave w holds col-tiles {2w,2w+1};
// LDS only for the A tile (16KB).
// ---------------------------------------------------------------------------
__global__ __launch_bounds__(256) void mgemm1_k(
    const float* __restrict__ x, const short* __restrict__ wf,
    u16* __restrict__ p1, int M)
{
    constexpr int KD = 128, NC = 128, KC = 4, KQ = 32;
    __shared__ short Asl[64 * KD];
    const int t = threadIdx.x;
    const int l = t & 63;
    const int w = t >> 6;

    short8 B[2][KC];
#pragma unroll
    for (int c = 0; c < 2; c++)
#pragma unroll
        for (int kc = 0; kc < KC; kc++)
            B[c][kc] = *(const short8*)&wf[(((w * 2 + c) * KC + kc) * 64 + l) * 8];

    {
        const int r = t >> 2;
        const int q = t & 3;
        const int grow = blockIdx.x * 64 + r;
        const int rt = r >> 4;
        u16 hv[KQ];
        if (grow < M) {
            const float* ap = x + (size_t)grow * KD + q * KQ;
#pragma unroll
            for (int i = 0; i < KQ / 4; i++) {
                const float4 v = ((const float4*)ap)[i];
                hv[i * 4 + 0] = f2bf(v.x); hv[i * 4 + 1] = f2bf(v.y);
                hv[i * 4 + 2] = f2bf(v.z); hv[i * 4 + 3] = f2bf(v.w);
            }
        } else {
#pragma unroll
            for (int i = 0; i < KQ; i++) hv[i] = 0;
        }
#pragma unroll
        for (int gg = 0; gg < KQ / 8; gg++) {
            const int k0 = q * KQ + gg * 8;
            const int kc = k0 >> 5;
            const int lane = (r & 15) + ((k0 >> 3) & 3) * 16;
            *(short8*)&Asl[((rt * KC + kc) * 64 + lane) * 8] = *(short8*)&hv[gg * 8];
        }
    }
    __syncthreads();

    f32x4 acc[4][2];
#pragma unroll
    for (int rt = 0; rt < 4; rt++)
#pragma unroll
        for (int c = 0; c < 2; c++) acc[rt][c] = (f32x4){0.f, 0.f, 0.f, 0.f};

#pragma unroll
    for (int kc = 0; kc < KC; kc++)
#pragma unroll
        for (int rt = 0; rt < 4; rt++) {
            const short8 x0 = *(const short8*)&Asl[((rt * KC + kc) * 64 + l) * 8];
            acc[rt][0] = __builtin_amdgcn_mfma_f32_16x16x32_bf16(B[0][kc], x0, acc[rt][0], 0, 0, 0);
            acc[rt][1] = __builtin_amdgcn_mfma_f32_16x16x32_bf16(B[1][kc], x0, acc[rt][1], 0, 0, 0);
        }

    const int cbase = (l >> 4) * 4;
#pragma unroll
    for (int rt = 0; rt < 4; rt++) {
        const int grow = blockIdx.x * 64 + rt * 16 + (l & 15);
        if (grow < M) {
#pragma unroll
            for (int c = 0; c < 2; c++) {
                short4v o16;
#pragma unroll
                for (int j = 0; j < 4; j++) o16[j] = (short)f2bf(acc[rt][c][j]);
                *(short4v*)&p1[(size_t)grow * NC + (w * 2 + c) * 16 + cbase] = o16;
            }
        }
    }
}

// ---------------------------------------------------------------------------
// FUSED mgemm23 (reg-B both stages): p2 = (relu(BN(s1))@w1b+b1b, relu) @ w2a
// BN stats arrive as fixed-point u64 (scale 2^24).
// ---------------------------------------------------------------------------
__global__ __launch_bounds__(256) void mgemm23_k(
    const u16* __restrict__ s1, const short* __restrict__ w1bf,
    const short* __restrict__ w2af,
    const u64* __restrict__ sum, const u64* __restrict__ sumsq,
    const float* __restrict__ g, const float* __restrict__ be, float invN,
    const float* __restrict__ b1b, u16* __restrict__ p2, int M)
{
    constexpr int KD = 128, NO = 64, KC = 4, KQ = 32;
    __shared__ short Asl[64 * KD];
    __shared__ float scb[KD];
    __shared__ float shb[KD];

    const int t = threadIdx.x;
    const int l = t & 63;
    const int w = t >> 6;

    short8 B1[2][KC];
    short8 B2[KC];
#pragma unroll
    for (int c = 0; c < 2; c++)
#pragma unroll
        for (int kc = 0; kc < KC; kc++)
            B1[c][kc] = *(const short8*)&w1bf[(((w * 2 + c) * KC + kc) * 64 + l) * 8];
#pragma unroll
    for (int kc = 0; kc < KC; kc++)
        B2[kc] = *(const short8*)&w2af[((w * KC + kc) * 64 + l) * 8];

    if (t < KD) {
        const float m = (float)((s64)sum[t]) * FXI * invN;
        const float v = (float)((s64)sumsq[t]) * FXI * invN - m * m;
        const float r = rsqrtf(v + 1e-5f);
        const float s = g[t] * r;
        scb[t] = s;
        shb[t] = be[t] - m * s;
    }
    __syncthreads();

    {
        const int r = t >> 2;
        const int q = t & 3;
        const int grow = blockIdx.x * 64 + r;
        const int rt = r >> 4;
        u16 hv[KQ];
        if (grow < M) {
            const u16* ap = s1 + (size_t)grow * KD + q * KQ;
#pragma unroll
            for (int i = 0; i < KQ / 8; i++)
                *(short8*)&hv[i * 8] = ((const short8*)ap)[i];
#pragma unroll
            for (int i = 0; i < KQ; i++) {
                const int k = q * KQ + i;
                hv[i] = f2bf(fmaxf(0.f, bf2f(hv[i]) * scb[k] + shb[k]));
            }
        } else {
#pragma unroll
            for (int i = 0; i < KQ; i++) hv[i] = 0;
        }
#pragma unroll
        for (int gg = 0; gg < KQ / 8; gg++) {
            const int k0 = q * KQ + gg * 8;
            const int kc = k0 >> 5;
            const int lane = (r & 15) + ((k0 >> 3) & 3) * 16;
            *(short8*)&Asl[((rt * KC + kc) * 64 + lane) * 8] = *(short8*)&hv[gg * 8];
        }
    }
    __syncthreads();

    f32x4 acc[4][2];
#pragma unroll
    for (int rt = 0; rt < 4; rt++)
#pragma unroll
        for (int c = 0; c < 2; c++) acc[rt][c] = (f32x4){0.f, 0.f, 0.f, 0.f};
#pragma unroll
    for (int kc = 0; kc < KC; kc++)
#pragma unroll
        for (int rt = 0; rt < 4; rt++) {
            const short8 x0 = *(const short8*)&Asl[((rt * KC + kc) * 64 + l) * 8];
            acc[rt][0] = __builtin_amdgcn_mfma_f32_16x16x32_bf16(B1[0][kc], x0, acc[rt][0], 0, 0, 0);
            acc[rt][1] = __builtin_amdgcn_mfma_f32_16x16x32_bf16(B1[1][kc], x0, acc[rt][1], 0, 0, 0);
        }
    __syncthreads();

    {
        const int cb4 = l >> 4;
#pragma unroll
        for (int rt = 0; rt < 4; rt++) {
            const int row = rt * 16 + (l & 15);
            const int sw = (row & 7) << 1;
#pragma unroll
            for (int c = 0; c < 2; c++) {
                const int ct = w * 2 + c;
                const float4 bv = *(const float4*)&b1b[ct * 16 + cb4 * 4];
                short4v o16;
                o16[0] = (short)f2bf(fmaxf(acc[rt][c][0] + bv.x, 0.f));
                o16[1] = (short)f2bf(fmaxf(acc[rt][c][1] + bv.y, 0.f));
                o16[2] = (short)f2bf(fmaxf(acc[rt][c][2] + bv.z, 0.f));
                o16[3] = (short)f2bf(fmaxf(acc[rt][c][3] + bv.w, 0.f));
                const int gsw = (ct * 4 + cb4) ^ sw;
                *(short4v*)&Asl[row * 128 + gsw * 4] = o16;
            }
        }
    }
    __syncthreads();

    f32x4 acc2[4];
#pragma unroll
    for (int rt = 0; rt < 4; rt++) acc2[rt] = (f32x4){0.f, 0.f, 0.f, 0.f};
#pragma unroll
    for (int kc = 0; kc < KC; kc++)
#pragma unroll
        for (int rt = 0; rt < 4; rt++) {
            const int row = rt * 16 + (l & 15);
            const int G = kc * 8 + (l >> 4) * 2;
            const int Gs = G ^ ((row & 7) << 1);
            const short8 x0 = *(const short8*)&Asl[row * 128 + Gs * 4];
            acc2[rt] = __builtin_amdgcn_mfma_f32_16x16x32_bf16(B2[kc], x0, acc2[rt], 0, 0, 0);
        }

    {
        const int cbase = (l >> 4) * 4;
#pragma unroll
        for (int rt = 0; rt < 4; rt++) {
            const int grow = blockIdx.x * 64 + rt * 16 + (l & 15);
            if (grow < M) {
                short4v o16;
#pragma unroll
                for (int j = 0; j < 4; j++) o16[j] = (short)f2bf(acc2[rt][j]);
                *(short4v*)&p2[(size_t)grow * NO + w * 16 + cbase] = o16;
            }
        }
    }
}

// ---------------------------------------------------------------------------
// mgemm4: out = log_softmax( relu(BN(s2)) @ w2b + b2b ).
// ---------------------------------------------------------------------------
__global__ __launch_bounds__(256) void mgemm4_k(
    const u16* __restrict__ s2, const short* __restrict__ Wf,
    const u64* __restrict__ sum, const u64* __restrict__ sumsq,
    const float* __restrict__ g, const float* __restrict__ be, float invN,
    const float* __restrict__ bias, float* __restrict__ outp, int M)
{
    constexpr int KD = 64, NC = 64, KC = 2, CT = 4, KQ = 16;
    __shared__ short Asl[64 * KD];
    __shared__ short Bsl[NC * KD];
    __shared__ float scb[KD];
    __shared__ float shb[KD];

    const int t = threadIdx.x;
    const int l = t & 63;
    const int w = t >> 6;

    if (t < KD) {
        const float m = (float)((s64)sum[t]) * FXI * invN;
        const float v = (float)((s64)sumsq[t]) * FXI * invN - m * m;
        const float r = rsqrtf(v + 1e-5f);
        const float s = g[t] * r;
        scb[t] = s;
        shb[t] = be[t] - m * s;
    }
    __syncthreads();

    {
        const float4* src = (const float4*)Wf;
        float4* dst = (float4*)Bsl;
#pragma unroll
        for (int u = t; u < NC * KD / 8; u += 256) dst[u] = src[u];
    }
    {
        const int r = t >> 2;
        const int q = t & 3;
        const int grow = blockIdx.x * 64 + r;
        const int rt = r >> 4;
        u16 hv[KQ];
        if (grow < M) {
            const u16* ap = s2 + (size_t)grow * KD + q * KQ;
#pragma unroll
            for (int i = 0; i < KQ / 8; i++)
                *(short8*)&hv[i * 8] = ((const short8*)ap)[i];
#pragma unroll
            for (int i = 0; i < KQ; i++) {
                const int k = q * KQ + i;
                hv[i] = f2bf(fmaxf(0.f, bf2f(hv[i]) * scb[k] + shb[k]));
            }
        } else {
#pragma unroll
            for (int i = 0; i < KQ; i++) hv[i] = 0;
        }
#pragma unroll
        for (int gg = 0; gg < KQ / 8; gg++) {
            const int k0 = q * KQ + gg * 8;
            const int kc = k0 >> 5;
            const int lane = (r & 15) + ((k0 >> 3) & 3) * 16;
            *(short8*)&Asl[((rt * KC + kc) * 64 + lane) * 8] = *(short8*)&hv[gg * 8];
        }
    }
    __syncthreads();

    f32x4 acc[CT];
#pragma unroll
    for (int c = 0; c < CT; c++) acc[c] = (f32x4){0.f, 0.f, 0.f, 0.f};
#pragma unroll
    for (int kc = 0; kc < KC; kc++) {
        const short8 x0 = *(const short8*)&Asl[((w * KC + kc) * 64 + l) * 8];
#pragma unroll
        for (int ct = 0; ct < CT; ct++) {
            const short8 wb = *(const short8*)&Bsl[((ct * KC + kc) * 64 + l) * 8];
            acc[ct] = __builtin_amdgcn_mfma_f32_16x16x32_bf16(wb, x0, acc[ct], 0, 0, 0);
        }
    }

    const int cbase = (l >> 4) * 4;
    const int grow = blockIdx.x * 64 + w * 16 + (l & 15);
    float v[CT * 4];
#pragma unroll
    for (int ct = 0; ct < CT; ct++) {
        const float4 bv = *(const float4*)&bias[ct * 16 + cbase];
        v[ct * 4 + 0] = acc[ct][0] + bv.x;
        v[ct * 4 + 1] = acc[ct][1] + bv.y;
        v[ct * 4 + 2] = acc[ct][2] + bv.z;
        v[ct * 4 + 3] = acc[ct][3] + bv.w;
    }
    float m = v[0];
#pragma unroll
    for (int j = 1; j < CT * 4; j++) m = fmaxf(m, v[j]);
    m = fmaxf(m, __shfl_xor(m, 16));
    m = fmaxf(m, __shfl_xor(m, 32));
    float s = 0.f;
#pragma unroll
    for (int j = 0; j < CT * 4; j++) s += __expf(v[j] - m);
    s += __shfl_xor(s, 16);
    s += __shfl_xor(s, 32);
    const float lg = m + __logf(s);
    if (grow < M) {
#pragma unroll
        for (int ct = 0; ct < CT; ct++) {
            f32x4 o;
#pragma unroll
            for (int j = 0; j < 4; j++) o[j] = v[ct * 4 + j] - lg;
            *(f32x4*)&outp[(size_t)grow * NC + ct * 16 + cbase] = o;
        }
    }
}

// ---------------------------------------------------------------------------
// CSR build: histogram (also zeroes agg), ONE-kernel scan, bucket fill.
// ---------------------------------------------------------------------------
__global__ __launch_bounds__(256) void hist_k(const int* __restrict__ ei,
                                              int* __restrict__ cnt,
                                              int* __restrict__ agg, int E)
{
    const int gid = blockIdx.x * blockDim.x + threadIdx.x;
    if (gid < 256) agg[gid] = 0;
    const int stride = gridDim.x * blockDim.x;
    for (int e = gid; e < E; e += stride) atomicAdd(&cnt[ei[E + e]], 1);
}

__global__ __launch_bounds__(256) void scan1_k(const int* __restrict__ cnt,
                                               int* __restrict__ agg,
                                               int* __restrict__ off,
                                               int* __restrict__ cursor,
                                               int N, int E)
{
    __shared__ int part[256];
    __shared__ int redu[256];
    const int t = threadIdx.x;
    const int b = blockIdx.x;
    const int i = b * 256 + t;
    const int v = (i < N) ? cnt[i] : 0;
    part[t] = v;
    __syncthreads();
    for (int d = 1; d < 256; d <<= 1) {
        const int u = (t >= d) ? part[t - d] : 0;
        __syncthreads();
        part[t] += u;
        __syncthreads();
    }
    if (t == 0)
        __hip_atomic_store(&agg[b], part[255] | (1 << 30), __ATOMIC_RELEASE,
                           __HIP_MEMORY_SCOPE_AGENT);
    int loc = 0;
    for (int pb = t; pb < b; pb += 256) {
        int a;
        do {
            a = __hip_atomic_load(&agg[pb], __ATOMIC_ACQUIRE,
                                  __HIP_MEMORY_SCOPE_AGENT);
        } while (!(a & (1 << 30)));
        loc += a & ((1 << 30) - 1);
    }
    redu[t] = loc;
    __syncthreads();
    for (int s = 128; s; s >>= 1) {
        if (t < s) redu[t] += redu[t + s];
        __syncthreads();
    }
    const int base = redu[0];
    if (i < N) {
        const int o = base + part[t] - v;
        off[i] = o;
        cursor[i] = o;
    }
    if (b == 0 && t == 0) off[N] = E;
}

__global__ __launch_bounds__(256) void fill_k(const int* __restrict__ ei,
                                              int* __restrict__ cursor,
                                              int* __restrict__ srcs, int E)
{
    const int gid = blockIdx.x * blockDim.x + threadIdx.x;
    const int stride = gridDim.x * blockDim.x;
    for (int e = gid; e < E; e += stride) {
        const int s = ei[e];
        const int d = ei[E + e];
        const int pos = atomicAdd(&cursor[d], 1);
        srcs[pos] = s;
    }
}

// ---------------------------------------------------------------------------
// Gather segment-sum (bf16 in/out) + fused column stats.
// [R5 structure, BLKN=8 occupancy sweet spot]
// DETERMINISM: node sums in int32 fixed-point (scale 2^17) -- deterministic
// quantization + order-free integer addition = invariant to fill_k's
// nondeterministic bucket order. Stats via u64 fixed-point atomics.
// ---------------------------------------------------------------------------
template <int C>
__global__ __launch_bounds__(256) void segsum_bf(
    const u16* __restrict__ p, const int* __restrict__ off,
    const int* __restrict__ srcs, u16* __restrict__ out,
    u64* __restrict__ sum, u64* __restrict__ sumsq, int N)
{
    constexpr int BLKN = 8;            // nodes per wave
    constexpr int VPL = C / 64;        // channels per lane (2 or 1)
    __shared__ float red[4][64][2 * VPL];

    const int wv = threadIdx.x >> 6;
    const int l  = threadIdx.x & 63;
    const int base = blockIdx.x * 4 * BLKN;

    float ss[VPL], qq[VPL];
#pragma unroll
    for (int v = 0; v < VPL; v++) { ss[v] = 0.f; qq[v] = 0.f; }

    for (int i = 0; i < BLKN; i++) {
        const int n = base + i * 4 + wv;
        if (n < N) {
            const int lo = __builtin_amdgcn_readfirstlane(off[n]);
            const int hi = __builtin_amdgcn_readfirstlane(off[n + 1]);
            s32 acc[VPL];
            if constexpr (VPL == 2) {
                const u32 u = *(const u32*)&p[(size_t)n * C + 2 * l];
                acc[0] = f2fx32(bf2f((u16)u));
                acc[1] = f2fx32(bf2f((u16)(u >> 16)));
            } else {
                acc[0] = f2fx32(bf2f(p[(size_t)n * C + l]));
            }
            const int cnt = hi - lo;
            if (cnt > 0) {
                const int last = hi - 1;
                int idx[8];
#pragma unroll
                for (int j = 0; j < 8; j++) idx[j] = srcs[min(lo + j, last)];
                for (int e = lo; e < hi; e += 8) {
                    int nx[8];
#pragma unroll
                    for (int j = 0; j < 8; j++)
                        nx[j] = srcs[min(e + 8 + j, last)];   // prefetch next
#pragma unroll
                    for (int j = 0; j < 8; j++) {
                        const bool live = (e + j) < hi;
                        if constexpr (VPL == 2) {
                            const u32 u = *(const u32*)&p[(size_t)idx[j] * C + 2 * l];
                            const s32 t0 = f2fx32(bf2f((u16)u));
                            const s32 t1 = f2fx32(bf2f((u16)(u >> 16)));
                            acc[0] += live ? t0 : 0;
                            acc[1] += live ? t1 : 0;
                        } else {
                            const s32 t0 = f2fx32(bf2f(p[(size_t)idx[j] * C + l]));
                            acc[0] += live ? t0 : 0;
                        }
                    }
#pragma unroll
                    for (int j = 0; j < 8; j++) idx[j] = nx[j];
                }
            }
            // fixed->float (one deterministic rounding), bf16 round, store
            if constexpr (VPL == 2) {
                const u16 r0 = f2bf((float)acc[0] * FXI2);
                const u16 r1 = f2bf((float)acc[1] * FXI2);
                *(u32*)&out[(size_t)n * C + 2 * l] = (u32)r0 | ((u32)r1 << 16);
                const float f0 = bf2f(r0), f1 = bf2f(r1);
                ss[0] += f0; qq[0] += f0 * f0;
                ss[1] += f1; qq[1] += f1 * f1;
            } else {
                const u16 r = f2bf((float)acc[0] * FXI2);
                out[(size_t)n * C + l] = r;
                const float f = bf2f(r);
                ss[0] += f; qq[0] += f * f;
            }
        }
    }

    // block reduce (fixed order) -> u64 fixed-point atomics (order-free)
#pragma unroll
    for (int v = 0; v < VPL; v++) {
        red[wv][l][2 * v] = ss[v];
        red[wv][l][2 * v + 1] = qq[v];
    }
    __syncthreads();
    if (wv == 0) {
#pragma unroll
        for (int v = 0; v < VPL; v++) {
            float a = 0.f, b = 0.f;
#pragma unroll
            for (int w2 = 0; w2 < 4; w2++) {
                a += red[w2][l][2 * v];
                b += red[w2][l][2 * v + 1];
            }
            const int ch = (VPL == 2) ? (2 * l + v) : l;
            atomicAdd(&sum[ch], (u64)(s64)(a * FXS));
            atomicAdd(&sumsq[ch], (u64)(s64)(b * FXS));
        }
    }
}

extern "C" void kernel_launch(void* const* d_in, const int* in_sizes, int n_in,
                              void* d_out, int out_size, void* d_ws, size_t ws_size,
                              hipStream_t stream)
{
    const float* x   = (const float*)d_in[0];
    const int*   ei  = (const int*)d_in[1];
    const float* w1a = (const float*)d_in[2];
    // d_in[3] = b1a: cancelled by BN
    const float* g1  = (const float*)d_in[4];
    const float* be1 = (const float*)d_in[5];
    const float* w1b = (const float*)d_in[6];
    const float* b1b = (const float*)d_in[7];
    const float* w2a = (const float*)d_in[8];
    // d_in[9] = b2a: cancelled by BN
    const float* g2  = (const float*)d_in[10];
    const float* be2 = (const float*)d_in[11];
    const float* w2b = (const float*)d_in[12];
    const float* b2b = (const float*)d_in[13];
    float* out = (float*)d_out;

    const int N = in_sizes[0] / 128;   // 50000
    const int E = in_sizes[1] / 2;     // 800000

    // ---- workspace layout ----
    u16* buf1 = (u16*)d_ws;                      // N*128 bf16 : p1, then p2
    u16* buf2 = buf1 + (size_t)N * 128;          // N*128 bf16 : s1, then s2
    u64* statsll = (u64*)(buf2 + (size_t)N * 128);   // 384 u64 (fixed-point)
    u64* sum1 = statsll,       *sq1 = statsll + 128;
    u64* sum2 = statsll + 256, *sq2 = statsll + 320;
    int* cnt    = (int*)(statsll + 384);         // N
    int* off    = cnt + N;                       // N+1
    int* cursor = off + N + 1;                   // N
    int* srcs   = cursor + N;                    // E
    int* agg    = srcs + E;                      // 256 (scan aggregates)
    int* pad    = agg + 256;                     // 256 (alignment pad)
    short* w1af = (short*)(pad + 256);           // 128*128
    short* w1bf = w1af + 128 * 128;              // 128*128
    short* w2af = w1bf + 128 * 128;              // 128*64
    short* w2bf = w2af + 128 * 64;               // 64*64
    u16* p1 = buf1;
    u16* s1 = buf2;
    u16* p2 = buf1;                    // reuse: p1 dead after segsum1
    u16* s2 = buf2;                    // reuse: s1 dead after mgemm23

    hipMemsetAsync(statsll, 0, 384 * sizeof(u64) + (size_t)N * sizeof(int), stream);

    const int G1 = (N + 255) / 256;    // 196 blocks <= 256 CUs: co-resident
    const int gb = (N + 63) / 64;      // BM=64 -> 782 blocks
    const int gs = (N + 31) / 32;      // segsum: 4 waves x 8 nodes per block
    const float invN = 1.f / N;

    // ---- CSR build ----
    hist_k<<<1024, 256, 0, stream>>>(ei, cnt, agg, E);
    scan1_k<<<G1, 256, 0, stream>>>(cnt, agg, off, cursor, N, E);
    fill_k<<<1024, 256, 0, stream>>>(ei, cursor, srcs, E);

    // ---- weight prep (one launch for all four) ----
    wprep4_k<<<22, 256, 0, stream>>>(w1a, w1b, w2a, w2b, w1af, w1bf, w2af, w2bf);

    // ---- Layer 1 ----
    mgemm1_k<<<gb, 256, 0, stream>>>(x, w1af, p1, N);
    segsum_bf<128><<<gs, 256, 0, stream>>>(p1, off, srcs, s1, sum1, sq1, N);

    // ---- Fused: h1 = relu(BN(s1)@w1b+b1b); p2 = h1@w2a ----
    mgemm23_k<<<gb, 256, 0, stream>>>(s1, w1bf, w2af, sum1, sq1, g1, be1,
                                      invN, b1b, p2, N);

    // ---- Layer 2 aggregation + output ----
    segsum_bf<64><<<gs, 256, 0, stream>>>(p2, off, srcs, s2, sum2, sq2, N);
    mgemm4_k<<<gb, 256, 0, stream>>>(s2, w2bf, sum2, sq2, g2, be2, invN, b2b,
                                     out, N);
}